// Round 4
// baseline (604.204 us; speedup 1.0000x reference)
//
#include <hip/hip_runtime.h>
#include <hip/hip_bf16.h>

typedef __attribute__((ext_vector_type(8))) short short8;
typedef __attribute__((ext_vector_type(4))) float f32x4;

#define NTOP 1000
#define KC   256
#define MROWS 40000

static __device__ __forceinline__ unsigned short f2bf(float x) {
    union { float f; unsigned u; } v; v.f = x;
    unsigned r = (v.u + 0x7FFFu + ((v.u >> 16) & 1u)) >> 16;
    return (unsigned short)r;
}

// Kernel 1: colsum[j] += sum over an 8-row slab of nw. colsum pre-zeroed by memset.
__global__ void k_prep(const float* __restrict__ nw,
                       float* __restrict__ colsum) {
    int j  = blockIdx.x * 256 + threadIdx.x;
    int i0 = blockIdx.y * 8;
    if (j < NTOP) {
        float s = 0.f;
        int iend = min(i0 + 8, NTOP);
        for (int i = i0; i < iend; ++i) s += nw[(size_t)i * NTOP + j];
        atomicAdd(colsum + j, s);
    }
}

// Kernel 2: build B' in MFMA-fragment order:
//   B'[((nt*8 + s)*64 + lane)] (short8) = V_j[n = nt*16 + (lane&15),
//                                             k = s*32 + (lane>>4)*8 + j]
__global__ void k_vj(const float* __restrict__ V,
                     const float* __restrict__ noise,
                     const float* __restrict__ colsum,
                     unsigned short* __restrict__ Bp) {
    int t  = blockIdx.x * 256 + threadIdx.x;   // 0 .. 32767
    int nt = t >> 9;
    int s  = (t >> 6) & 7;
    int l  = t & 63;
    int lm = l & 15, lq = l >> 4;
    int n  = nt * 16 + lm;
    int k0 = s * 32 + lq * 8;
    union { short8 v; unsigned short us[8]; } pk;
    if (n < NTOP) {
        float cs = colsum[n];
        #pragma unroll
        for (int j = 0; j < 8; ++j) {
            int idx = n * KC + k0 + j;
            pk.us[j] = f2bf(V[idx] * cs + 0.1f * noise[idx]);
        }
    } else {
        #pragma unroll
        for (int j = 0; j < 8; ++j) pk.us[j] = 0;
    }
    reinterpret_cast<short8*>(Bp)[t] = pk.v;
}

// Kernel 2b: compress C (int32 0/1, 160 MB) into bitmask maskT[32][MROWS] (5 MB).
// maskT[hs][m] bit b  <=>  C[m][hs*32 + b] == 1.  Coalesced in, LDS-transposed,
// coalesced out.
__global__ __launch_bounds__(256) void k_cmask(const int* __restrict__ C,
                                               unsigned int* __restrict__ maskT) {
    __shared__ unsigned int lmask[32][64];
    const int rbase = blockIdx.x * 64;
    const int t = threadIdx.x;
    const int mrow = rbase + (t >> 2);     // 64 rows per block
    const int q = t & 3;                   // quarter: hs in [q*8, q*8+8)
    const int* crow = C + (size_t)mrow * NTOP;
    for (int hs = q * 8; hs < q * 8 + 8; ++hs) {
        unsigned int w = 0;
        #pragma unroll
        for (int i = 0; i < 8; ++i) {
            int col = hs * 32 + i * 4;
            if (col + 3 < NTOP) {
                int4 v = *reinterpret_cast<const int4*>(crow + col);
                w |= (v.x == 1 ? 1u : 0u) << (i * 4 + 0);
                w |= (v.y == 1 ? 1u : 0u) << (i * 4 + 1);
                w |= (v.z == 1 ? 1u : 0u) << (i * 4 + 2);
                w |= (v.w == 1 ? 1u : 0u) << (i * 4 + 3);
            }
        }
        lmask[hs][t >> 2] = w;
    }
    __syncthreads();
    // write out: thread t -> (hs = t>>3, chunk = t&7) writes 8 words coalesced
    const int hs = t >> 3, ch = t & 7;
    const int4* src = reinterpret_cast<const int4*>(&lmask[hs][ch * 8]);
    int4* dst = reinterpret_cast<int4*>(maskT + (size_t)hs * MROWS + rbase + ch * 8);
    dst[0] = src[0];
    dst[1] = src[1];
}

// ---------------- k_main v5 ----------------
// 64 M-rows/block (4 waves x 16). Per half-step (32 n-cols):
//  - Bf 16 KB half-tile: async global_load_lds, double buffered (as v4)
//  - R  8 KB [64 rows][32 cols]: async global_load_lds, double buffered,
//    SOURCE-swizzled (chunk ^ (row&7)) so the swizzled LDS read is conflict-free
//    (rule 21: linear dest + inverse-swz source + swz read)
//  - C replaced by 1 broadcast mask-word line per wave per iter
// Scattered-transaction count per iter drops ~8x vs v4.
__global__ __launch_bounds__(256, 3) void k_main(
    const float* __restrict__ U, const float* __restrict__ w5,
    const float* __restrict__ b1, const short8* __restrict__ Bf,
    const float* __restrict__ R, const unsigned int* __restrict__ maskT,
    float* __restrict__ out)
{
    __shared__ short8 BfL[2][1024];   // 2 x 16 KB
    __shared__ float4 RL[2][512];     // 2 x 8 KB : [buf][row*8 + swz_chunk]
    __shared__ float  red[4];

    const int tid  = threadIdx.x;
    const int wave = tid >> 6;
    const int l    = tid & 63;
    const int lm = l & 15;
    const int lq = l >> 4;
    const int rbase = blockIdx.x << 6;
    const int m  = rbase + (wave << 4) + lm;

    // ---- async stage helpers ----
    auto stageBf = [&](int buf, int hs) {
        const char* src = (const char*)Bf + ((size_t)hs << 14) + (size_t)tid * 16;
        char*       dst = (char*)&BfL[buf][0] + (size_t)tid * 16;
        #pragma unroll
        for (int i = 0; i < 4; ++i) {
            __builtin_amdgcn_global_load_lds(
                (const __attribute__((address_space(1))) unsigned int*)(src + i * 4096),
                (__attribute__((address_space(3))) unsigned int*)(dst + i * 4096),
                16, 0, 0);
        }
    };
    auto stageR = [&](int buf, int hs) {
        #pragma unroll
        for (int p = 0; p < 2; ++p) {
            const int S    = (wave * 2 + p) * 64 + l;   // slot 0..511
            const int row  = S >> 3;
            const int csrc = (S & 7) ^ (row & 7);       // inverse-swizzled source
            int off = hs * 128 + csrc * 16;
            off = off < 3984 ? off : 3984;              // clamp (hs=31 tail), masked later
            const char* src = (const char*)R + (size_t)(rbase + row) * 4000 + off;
            char*       dst = (char*)&RL[buf][0] + (size_t)S * 16;
            __builtin_amdgcn_global_load_lds(
                (const __attribute__((address_space(1))) unsigned int*)src,
                (__attribute__((address_space(3))) unsigned int*)dst,
                16, 0, 0);
        }
    };

    // ---- prologue: stage hs=0 (async), then build A-fragments (hides latency) ----
    stageBf(0, 0);
    stageR(0, 0);

    const float w0 = w5[0], w1 = w5[1], w2 = w5[2], w3 = w5[3], w4 = w5[4];
    const float bb = b1[0];
    short8 afr[8];
    #pragma unroll
    for (int s = 0; s < 8; ++s) {
        const float4* up4 = reinterpret_cast<const float4*>(
            U + (size_t)(m * KC + s * 32 + lq * 8) * 5);
        float u[40];
        #pragma unroll
        for (int i = 0; i < 10; ++i) {
            float4 t4 = up4[i];
            u[i*4+0] = t4.x; u[i*4+1] = t4.y; u[i*4+2] = t4.z; u[i*4+3] = t4.w;
        }
        union { short8 v; unsigned short us[8]; } pk;
        #pragma unroll
        for (int j = 0; j < 8; ++j) {
            const float* uu = u + j * 5;
            float e = uu[0]*w0 + uu[1]*w1 + uu[2]*w2 + uu[3]*w3 + uu[4]*w4 + bb;
            pk.us[j] = f2bf(e);
        }
        afr[s] = pk.v;
    }

    __syncthreads();   // vmcnt drain: buf0 (Bf + R) staged

    float lpsum = 0.f;

    for (int hs = 0; hs < 32; ++hs) {
        const int cur = hs & 1;

        // mask word: 1 line per wave (4 lanes share a word), consumed in epilogue
        const unsigned int mw = maskT[(size_t)hs * MROWS + m];

        if (hs < 31) { stageBf(cur ^ 1, hs + 1); stageR(cur ^ 1, hs + 1); }

        f32x4 acc[2];
        acc[0] = (f32x4){0.f, 0.f, 0.f, 0.f};
        acc[1] = (f32x4){0.f, 0.f, 0.f, 0.f};

        #pragma unroll
        for (int s = 0; s < 8; ++s) {
            #pragma unroll
            for (int t2 = 0; t2 < 2; ++t2) {
                const short8 bfr = BfL[cur][((t2 * 8 + s) << 6) + l];
                acc[t2] = __builtin_amdgcn_mfma_f32_16x16x32_bf16(bfr, afr[s], acc[t2], 0, 0, 0);
            }
        }

        // Epilogue: lane owns row m; cols n = hs*32 + t2*16 + lq*4 + r
        #pragma unroll
        for (int t2 = 0; t2 < 2; ++t2) {
            const int row  = (wave << 4) + lm;
            const int slot = (row << 3) + (((t2 << 2) + lq) ^ (lm & 7));  // swz read
            const float4 r4 = RL[cur][slot];
            const float* rp = reinterpret_cast<const float*>(&r4);
            #pragma unroll
            for (int r = 0; r < 4; ++r) {
                const int bit = t2 * 16 + lq * 4 + r;
                float x   = acc[t2][r];
                float muv = 1.f / (1.f + __expf(-x));
                float d   = rp[r] - muv;
                float lp  = -50.f * d * d + 1.3836465597893728f;
                if ((mw >> bit) & 1u) lpsum += lp;
            }
        }

        __syncthreads();   // readers done with cur; next-buf stages drained
    }

    #pragma unroll
    for (int off = 32; off > 0; off >>= 1) lpsum += __shfl_down(lpsum, off);
    if (l == 0) red[wave] = lpsum;
    __syncthreads();
    if (tid == 0) atomicAdd(out, red[0] + red[1] + red[2] + red[3]);
}

// ---------------- fallback (v4 path) if workspace is too small ----------------
__global__ __launch_bounds__(256, 4) void k_main_fb(
    const float* __restrict__ U, const float* __restrict__ w5,
    const float* __restrict__ b1, const short8* __restrict__ Bf,
    const float* __restrict__ R, const int* __restrict__ C,
    float* __restrict__ out)
{
    __shared__ short8 BfL[2][1024];
    __shared__ float  red[4];

    const int tid  = threadIdx.x;
    const int wave = tid >> 6;
    const int l    = tid & 63;
    const int lm = l & 15;
    const int lq = l >> 4;
    const int m  = (blockIdx.x << 6) + (wave << 4) + lm;

    {
        const char* src = (const char*)Bf + (size_t)tid * 16;
        char*       dst = (char*)&BfL[0][0] + (size_t)tid * 16;
        #pragma unroll
        for (int i = 0; i < 4; ++i) {
            __builtin_amdgcn_global_load_lds(
                (const __attribute__((address_space(1))) unsigned int*)(src + i * 4096),
                (__attribute__((address_space(3))) unsigned int*)(dst + i * 4096),
                16, 0, 0);
        }
    }

    const float w0 = w5[0], w1 = w5[1], w2 = w5[2], w3 = w5[3], w4 = w5[4];
    const float bb = b1[0];
    short8 afr[8];
    #pragma unroll
    for (int s = 0; s < 8; ++s) {
        const float4* up4 = reinterpret_cast<const float4*>(
            U + (size_t)(m * KC + s * 32 + lq * 8) * 5);
        float u[40];
        #pragma unroll
        for (int i = 0; i < 10; ++i) {
            float4 t4 = up4[i];
            u[i*4+0] = t4.x; u[i*4+1] = t4.y; u[i*4+2] = t4.z; u[i*4+3] = t4.w;
        }
        union { short8 v; unsigned short us[8]; } pk;
        #pragma unroll
        for (int j = 0; j < 8; ++j) {
            const float* uu = u + j * 5;
            float e = uu[0]*w0 + uu[1]*w1 + uu[2]*w2 + uu[3]*w3 + uu[4]*w4 + bb;
            pk.us[j] = f2bf(e);
        }
        afr[s] = pk.v;
    }

    __syncthreads();

    float lpsum = 0.f;
    const size_t rowbase = (size_t)m * NTOP;

    for (int hs = 0; hs < 32; ++hs) {
        const int cur = hs & 1;
        float4 r4[2]; int4 c4[2];
        #pragma unroll
        for (int t = 0; t < 2; ++t) {
            int nb = (hs << 5) + t * 16 + (lq << 2);
            nb = nb < 996 ? nb : 996;
            r4[t] = *reinterpret_cast<const float4*>(R + rowbase + nb);
            c4[t] = *reinterpret_cast<const int4*>(C + rowbase + nb);
        }
        if (hs < 31) {
            const char* src = (const char*)Bf + ((size_t)(hs + 1) << 14) + (size_t)tid * 16;
            char*       dst = (char*)&BfL[cur ^ 1][0] + (size_t)tid * 16;
            #pragma unroll
            for (int i = 0; i < 4; ++i) {
                __builtin_amdgcn_global_load_lds(
                    (const __attribute__((address_space(1))) unsigned int*)(src + i * 4096),
                    (__attribute__((address_space(3))) unsigned int*)(dst + i * 4096),
                    16, 0, 0);
            }
        }
        f32x4 acc[2];
        acc[0] = (f32x4){0.f, 0.f, 0.f, 0.f};
        acc[1] = (f32x4){0.f, 0.f, 0.f, 0.f};
        #pragma unroll
        for (int s = 0; s < 8; ++s) {
            #pragma unroll
            for (int t = 0; t < 2; ++t) {
                const short8 bfr = BfL[cur][((t * 8 + s) << 6) + l];
                acc[t] = __builtin_amdgcn_mfma_f32_16x16x32_bf16(bfr, afr[s], acc[t], 0, 0, 0);
            }
        }
        #pragma unroll
        for (int t = 0; t < 2; ++t) {
            const int nb0 = (hs << 5) + t * 16 + (lq << 2);
            if (nb0 < NTOP) {
                const float* rp = reinterpret_cast<const float*>(&r4[t]);
                const int*   cp = reinterpret_cast<const int*>(&c4[t]);
                #pragma unroll
                for (int r = 0; r < 4; ++r) {
                    float x   = acc[t][r];
                    float muv = 1.f / (1.f + __expf(-x));
                    float d   = rp[r] - muv;
                    float lp  = -50.f * d * d + 1.3836465597893728f;
                    lpsum += (cp[r] == 1) ? lp : 0.f;
                }
            }
        }
        __syncthreads();
    }

    #pragma unroll
    for (int off = 32; off > 0; off >>= 1) lpsum += __shfl_down(lpsum, off);
    if (l == 0) red[wave] = lpsum;
    __syncthreads();
    if (tid == 0) atomicAdd(out, red[0] + red[1] + red[2] + red[3]);
}

extern "C" void kernel_launch(void* const* d_in, const int* in_sizes, int n_in,
                              void* d_out, int out_size, void* d_ws, size_t ws_size,
                              hipStream_t stream) {
    const float* V     = (const float*)d_in[1];
    const float* R     = (const float*)d_in[2];
    const float* nw    = (const float*)d_in[3];
    const float* U     = (const float*)d_in[4];
    const float* w5    = (const float*)d_in[5];
    const float* b1    = (const float*)d_in[6];
    const float* noise = (const float*)d_in[7];
    const int*   C     = (const int*)d_in[8];
    float* out = (float*)d_out;

    float* colsum      = (float*)d_ws;
    unsigned short* Bp = (unsigned short*)((char*)d_ws + 8192);
    unsigned int* maskT = (unsigned int*)((char*)d_ws + 8192 + 524288);
    const size_t ws_needed = 8192 + 524288 + (size_t)32 * MROWS * 4;

    hipMemsetAsync(colsum, 0, NTOP * sizeof(float), stream);
    hipMemsetAsync(out, 0, sizeof(float), stream);
    hipLaunchKernelGGL(k_prep, dim3(4, 125), dim3(256), 0, stream, nw, colsum);
    hipLaunchKernelGGL(k_vj, dim3(128), dim3(256), 0, stream,
                       V, noise, colsum, Bp);

    if (ws_size >= ws_needed) {
        hipLaunchKernelGGL(k_cmask, dim3(MROWS / 64), dim3(256), 0, stream, C, maskT);
        hipLaunchKernelGGL(k_main, dim3(MROWS / 64), dim3(256), 0, stream,
                           U, w5, b1, (const short8*)Bp, R, maskT, out);
    } else {
        hipLaunchKernelGGL(k_main_fb, dim3(MROWS / 64), dim3(256), 0, stream,
                           U, w5, b1, (const short8*)Bp, R, C, out);
    }
}